// Round 1
// baseline (159.587 us; speedup 1.0000x reference)
//
#include <hip/hip_runtime.h>
#include <math.h>

#define NB 256        // batch = grid
#define N 128         // DIMX = DIMY = DIMH
#define NTHREADS 512  // 8 waves: thread = (k<<2)|h, k=0..127 row, h=0..3 K-quarter
#define MAX_IT 500
// LDS vectors: 4 slices of 32 floats, each padded to 40-float stride -> slice h
// starts at bank 8h so h-broadcast ds_read_b128s hit disjoint banks.
#define SLICE 40
#define SLOT(k) ((((k) >> 5) * SLICE) + ((k) & 31))
#define LDSVEC (3 * SLICE + 32)

// Cross-lane sums via DPP (no LDS/lgkm wait, ~4cy/step vs ~40cy ds_swizzle).
// 0xB1 = quad_perm(1,0,3,2) == xor1 ; 0x4E = quad_perm(2,3,0,1) == xor2
// -> bit-identical pairing to the old __shfl_xor(1)/__shfl_xor(2) version.
__device__ __forceinline__ float quad_sum(float p) {
    p += __int_as_float(__builtin_amdgcn_update_dpp(
            0, __float_as_int(p), 0xB1, 0xF, 0xF, true));
    p += __int_as_float(__builtin_amdgcn_update_dpp(
            0, __float_as_int(p), 0x4E, 0xF, 0xF, true));
    return p;
}
// Full 16-lane-row sum: quad_sum then row_ror:4 (0x124) + row_ror:8 (0x128).
// Cyclic rotates are sum-equivalent to xor swaps within a row.
__device__ __forceinline__ float row_sum16(float p) {
    p = quad_sum(p);
    p += __int_as_float(__builtin_amdgcn_update_dpp(
            0, __float_as_int(p), 0x124, 0xF, 0xF, true));
    p += __int_as_float(__builtin_amdgcn_update_dpp(
            0, __float_as_int(p), 0x128, 0xF, 0xF, true));
    return p;
}
__device__ __forceinline__ float softplus_f(float s) {
    float e = __expf(-fabsf(s));
    return fmaxf(s, 0.f) + __logf(1.f + e);
}
__device__ __forceinline__ float sigmoid_f(float s) {
    float e = __expf(-fabsf(s));
    float r = 1.f / (1.f + e);
    return s >= 0.f ? r : 1.f - r;
}

// row matvec for precompute: dot of W row k (global) with 128-vector V (LDS,
// slice-padded layout). Each lane sums its 32-slice, quad DPP-combine.
__device__ __forceinline__ float mv_row(const float* __restrict__ W,
                                        const float* __restrict__ V,
                                        int k, int h) {
    const float4* wr = (const float4*)(W + k * N + h * 32);
    const float4* vr = (const float4*)(V + h * SLICE);
    float q0 = 0.f, q1 = 0.f, q2 = 0.f, q3 = 0.f;
#pragma unroll
    for (int i = 0; i < 8; ++i) {
        float4 w = wr[i], v = vr[i];
        q0 = fmaf(w.x, v.x, q0); q1 = fmaf(w.y, v.y, q1);
        q2 = fmaf(w.z, v.z, q2); q3 = fmaf(w.w, v.w, q3);
    }
    return quad_sum((q0 + q1) + (q2 + q3));
}

__global__ __launch_bounds__(NTHREADS, 2)
void picnn_solve(const float* __restrict__ x, const float* __restrict__ y,
                 const float* __restrict__ wuu0_w, const float* __restrict__ wuu0_b,
                 const float* __restrict__ wyu0_w, const float* __restrict__ wyu0_b,
                 const float* __restrict__ wy0,
                 const float* __restrict__ wu0_w, const float* __restrict__ wu0_b,
                 const float* __restrict__ wuu1_w, const float* __restrict__ wuu1_b,
                 const float* __restrict__ wzu1_w, const float* __restrict__ wzu1_b,
                 const float* __restrict__ wz1,
                 const float* __restrict__ wyu1_w, const float* __restrict__ wyu1_b,
                 const float* __restrict__ wy1,
                 const float* __restrict__ wu1_w, const float* __restrict__ wu1_b,
                 const float* __restrict__ wzu2_w, const float* __restrict__ wzu2_b,
                 const float* __restrict__ wz2,
                 const float* __restrict__ wyu2_w, const float* __restrict__ wyu2_b,
                 const float* __restrict__ wy2,
                 float* __restrict__ out)
{
    const int b = blockIdx.x;
    const int t = threadIdx.x;
    const int k = t >> 2;   // output row 0..127
    const int h = t & 3;    // K-quarter 0..3
    const int lane = t & 63;

    __shared__ __align__(16) float xv[LDSVEC];
    __shared__ __align__(16) float u0v[LDSVEC];
    __shared__ __align__(16) float u1v[LDSVEC];
    __shared__ __align__(16) float a0s[LDSVEC];
    __shared__ __align__(16) float a1s[LDSVEC];
    __shared__ __align__(16) float y1s[LDSVEC];
    __shared__ __align__(16) float t1s[LDSVEC];
    __shared__ __align__(16) float d2s[LDSVEC];
    __shared__ __align__(16) float d1s[LDSVEC];
    __shared__ __align__(16) float rp[32];   // per-16-lane-row residual partials

    if (t < N) xv[SLOT(t)] = x[b * N + t];
    __syncthreads();

    // ---- per-sample iteration-invariant precompute ----
    float u0k = softplus_f(mv_row(wuu0_w, xv, k, h) + wuu0_b[k]);
    float a0k = mv_row(wyu0_w, xv, k, h) + wyu0_b[k];
    float c0  = mv_row(wu0_w,  xv, k, h) + wu0_b[k];
    if (h == 0) { u0v[SLOT(k)] = u0k; a0s[SLOT(k)] = a0k; }
    __syncthreads();

    float u1k = softplus_f(mv_row(wuu1_w, u0v, k, h) + wuu1_b[k]);
    float zu  = softplus_f(mv_row(wzu1_w, u0v, k, h) + wzu1_b[k]);
    float a1k = mv_row(wyu1_w, u0v, k, h) + wyu1_b[k];
    float c1  = mv_row(wu1_w,  u0v, k, h) + wu1_b[k];
    if (h == 0) { u1v[SLOT(k)] = u1k; a1s[SLOT(k)] = a1k; }
    __syncthreads();

    float a2 = mv_row(wyu2_w, u1v, k, h) + wyu2_b[k];
    float e2 = a2 * wy2[k];
    float dp;
    {
        // zu2 = sp(<wzu2_w, u1>): every quad computes the same full dot
        const float4* wr = (const float4*)(wzu2_w + h * 32);
        const float4* vr = (const float4*)(u1v + h * SLICE);
        float q0 = 0.f, q1 = 0.f, q2 = 0.f, q3 = 0.f;
#pragma unroll
        for (int i = 0; i < 8; ++i) {
            float4 w = wr[i], v = vr[i];
            q0 = fmaf(w.x, v.x, q0); q1 = fmaf(w.y, v.y, q1);
            q2 = fmaf(w.z, v.z, q2); q3 = fmaf(w.w, v.w, q3);
        }
        float zu2 = softplus_f(quad_sum((q0 + q1) + (q2 + q3)) + wzu2_b[0]);
        dp = zu2 * fmaxf(wz2[k], 0.f);
    }

    // ---- register-resident weights: rows (forward) + cols (backward) ----
    float4 wf0[8], wf1[8], wf2[8];  // wy0*a0col / clip(wz1) / wy1*a1col, row k
    float4 wb0[8], wb1[8], wb2[8];  // same matrices (unscaled), column k
    {
        const float4* r0 = (const float4*)(wy0 + k * N + h * 32);
        const float4* r1 = (const float4*)(wz1 + k * N + h * 32);
        const float4* r2 = (const float4*)(wy1 + k * N + h * 32);
#pragma unroll
        for (int i = 0; i < 8; ++i) {
            wf0[i] = r0[i];
            float4 z = r1[i];
            z.x = fmaxf(z.x, 0.f); z.y = fmaxf(z.y, 0.f);
            z.z = fmaxf(z.z, 0.f); z.w = fmaxf(z.w, 0.f);
            wf1[i] = z;
            wf2[i] = r2[i];
        }
#pragma unroll
        for (int i = 0; i < 8; ++i) {
            int r = h * 32 + 4 * i;
            wb0[i].x = wy0[(r + 0) * N + k]; wb0[i].y = wy0[(r + 1) * N + k];
            wb0[i].z = wy0[(r + 2) * N + k]; wb0[i].w = wy0[(r + 3) * N + k];
            wb1[i].x = fmaxf(wz1[(r + 0) * N + k], 0.f);
            wb1[i].y = fmaxf(wz1[(r + 1) * N + k], 0.f);
            wb1[i].z = fmaxf(wz1[(r + 2) * N + k], 0.f);
            wb1[i].w = fmaxf(wz1[(r + 3) * N + k], 0.f);
            wb2[i].x = wy1[(r + 0) * N + k]; wb2[i].y = wy1[(r + 1) * N + k];
            wb2[i].z = wy1[(r + 2) * N + k]; wb2[i].w = wy1[(r + 3) * N + k];
        }
        // Fold the iteration-invariant column scalings into the forward rows:
        //   s1  = wy0 (y1.*a0) + c0 = (wy0 diag(a0)) y1 + c0
        //   s2a = wy1 (y1.*a1)      = (wy1 diag(a1)) y1
        // -> S1 reads ONE vector (y1) instead of two, S4 writes one.
        const float4* a0r = (const float4*)(a0s + h * SLICE);
        const float4* a1r = (const float4*)(a1s + h * SLICE);
#pragma unroll
        for (int i = 0; i < 8; ++i) {
            float4 s0 = a0r[i], s1 = a1r[i];
            wf0[i].x *= s0.x; wf0[i].y *= s0.y; wf0[i].z *= s0.z; wf0[i].w *= s0.w;
            wf2[i].x *= s1.x; wf2[i].y *= s1.y; wf2[i].z *= s1.z; wf2[i].w *= s1.w;
        }
    }

    const float yk = y[b * N + k];
    // Initial guess zeroing the linear part of the residual:
    //   g = 0.5*y1 + e2 + (small NN backprop terms)  ->  y1_0 = 2*(y - e2)
    float y1v = 2.f * (yk - e2);
    if (h == 0) y1s[SLOT(k)] = y1v;
    __syncthreads();

    // Fixed-step gradient descent (alpha=1.25) on the 0.5-strongly-convex
    // objective. Convergence check is read one iteration late (top of loop,
    // from rp written in the previous S4) -> identical break iteration, but
    // the rp-read latency hides under the already-issued y1 slice loads.
    for (int it = 1; it <= MAX_IT; ++it) {
        // S1: issue y1 slice loads first, then resolve prev-iter convergence
        const float4* yr = (const float4*)(y1s + h * SLICE);
        float4 vv[8];
#pragma unroll
        for (int i = 0; i < 8; ++i) vv[i] = yr[i];
        if (it > 1) {
            const float4* rpv = (const float4*)rp;
            float4 ra = (rpv[0] + rpv[1]) + (rpv[2] + rpv[3]);
            float4 rb = (rpv[4] + rpv[5]) + (rpv[6] + rpv[7]);
            float4 u = ra + rb;                 // = 4*||r||^2 (prev iter)
            float tot = (u.x + u.y) + (u.z + u.w);
            if (tot < 4e-6f) break;  // per-sample ||r|| < 1e-3 (update applied)
        }
        // s1 = (wy0 diag(a0)) y1 + c0 ; s2a = (wy1 diag(a1)) y1  (one pass)
        float p0 = 0.f, p1 = 0.f, p2 = 0.f, p3 = 0.f;
        float q0 = 0.f, q1 = 0.f, q2 = 0.f, q3 = 0.f;
#pragma unroll
        for (int i = 0; i < 8; ++i) {
            float4 v = vv[i];
            p0 = fmaf(wf0[i].x, v.x, p0); p1 = fmaf(wf0[i].y, v.y, p1);
            p2 = fmaf(wf0[i].z, v.z, p2); p3 = fmaf(wf0[i].w, v.w, p3);
            q0 = fmaf(wf2[i].x, v.x, q0); q1 = fmaf(wf2[i].y, v.y, q1);
            q2 = fmaf(wf2[i].z, v.z, q2); q3 = fmaf(wf2[i].w, v.w, q3);
        }
        float s1v = quad_sum((p0 + p1) + (p2 + p3)) + c0;
        float s2a = quad_sum((q0 + q1) + (q2 + q3));
        float e1 = __expf(-fabsf(s1v));
        float z1 = fmaxf(s1v, 0.f) + __logf(1.f + e1);
        float rr1 = 1.f / (1.f + e1);
        float sig1 = (s1v >= 0.f) ? rr1 : 1.f - rr1;
        if (h == 0) t1s[SLOT(k)] = z1 * zu;
        __syncthreads();

        // S2: s2 = t1@wz1c^T + s2a + c1 ; d2 = dp*sigma(s2)
        const float4* t1r = (const float4*)(t1s + h * SLICE);
        p0 = p1 = p2 = p3 = 0.f;
#pragma unroll
        for (int i = 0; i < 8; ++i) {
            float4 v1 = t1r[i];
            p0 = fmaf(wf1[i].x, v1.x, p0); p1 = fmaf(wf1[i].y, v1.y, p1);
            p2 = fmaf(wf1[i].z, v1.z, p2); p3 = fmaf(wf1[i].w, v1.w, p3);
        }
        float s2 = quad_sum((p0 + p1) + (p2 + p3)) + s2a + c1;
        float d2 = dp * sigmoid_f(s2);
        if (h == 0) d2s[SLOT(k)] = d2;
        __syncthreads();

        // S3: q = d2@wz1c (cols) ; gc = d2@wy1 (cols) ; d1 = q*zu*sig1
        const float4* d2r = (const float4*)(d2s + h * SLICE);
        p0 = p1 = p2 = p3 = 0.f; q0 = q1 = q2 = q3 = 0.f;
#pragma unroll
        for (int i = 0; i < 8; ++i) {
            float4 d = d2r[i];
            p0 = fmaf(wb1[i].x, d.x, p0); p1 = fmaf(wb1[i].y, d.y, p1);
            p2 = fmaf(wb1[i].z, d.z, p2); p3 = fmaf(wb1[i].w, d.w, p3);
            q0 = fmaf(wb2[i].x, d.x, q0); q1 = fmaf(wb2[i].y, d.y, q1);
            q2 = fmaf(wb2[i].z, d.z, q2); q3 = fmaf(wb2[i].w, d.w, q3);
        }
        float qv = quad_sum((p0 + p1) + (p2 + p3));
        float gc = quad_sum((q0 + q1) + (q2 + q3));
        float d1 = qv * zu * sig1;
        if (h == 0) d1s[SLOT(k)] = d1;
        __syncthreads();

        // S4: gb = d1@wy0 (cols); g; fixed-step update; row residual partials
        const float4* d1r = (const float4*)(d1s + h * SLICE);
        p0 = p1 = p2 = p3 = 0.f;
#pragma unroll
        for (int i = 0; i < 8; ++i) {
            float4 d = d1r[i];
            p0 = fmaf(wb0[i].x, d.x, p0); p1 = fmaf(wb0[i].y, d.y, p1);
            p2 = fmaf(wb0[i].z, d.z, p2); p3 = fmaf(wb0[i].w, d.w, p3);
        }
        float gb = quad_sum((p0 + p1) + (p2 + p3));
        float g = fmaf(0.5f, y1v, e2) + gc * a1k + gb * a0k;
        float rres = yk - g;
        y1v = fmaf(1.25f, rres, y1v);
        if (h == 0) y1s[SLOT(k)] = y1v;
        float rs = row_sum16(rres * rres);   // 4 * sum over this row's 4 k's
        if ((lane & 15) == 0) rp[t >> 4] = rs;
        __syncthreads();
    }

    // out[b] = mean_k(y1 + y)
    __syncthreads();
    float v = row_sum16(y1v + yk);           // 4x duplicated per k
    if ((lane & 15) == 0) rp[t >> 4] = v;
    __syncthreads();
    if (t == 0) {
        const float4* rpv = (const float4*)rp;
        float4 ra = (rpv[0] + rpv[1]) + (rpv[2] + rpv[3]);
        float4 rb = (rpv[4] + rpv[5]) + (rpv[6] + rpv[7]);
        float4 u = ra + rb;
        out[b] = ((u.x + u.y) + (u.z + u.w)) * (1.f / 512.f);
    }
}

extern "C" void kernel_launch(void* const* d_in, const int* in_sizes, int n_in,
                              void* d_out, int out_size, void* d_ws, size_t ws_size,
                              hipStream_t stream) {
    const float* x      = (const float*)d_in[0];
    const float* y      = (const float*)d_in[1];
    const float* wuu0_w = (const float*)d_in[2];
    const float* wuu0_b = (const float*)d_in[3];
    const float* wyu0_w = (const float*)d_in[4];
    const float* wyu0_b = (const float*)d_in[5];
    const float* wy0    = (const float*)d_in[6];
    const float* wu0_w  = (const float*)d_in[7];
    const float* wu0_b  = (const float*)d_in[8];
    const float* wuu1_w = (const float*)d_in[9];
    const float* wuu1_b = (const float*)d_in[10];
    const float* wzu1_w = (const float*)d_in[11];
    const float* wzu1_b = (const float*)d_in[12];
    const float* wz1    = (const float*)d_in[13];
    const float* wyu1_w = (const float*)d_in[14];
    const float* wyu1_b = (const float*)d_in[15];
    const float* wy1    = (const float*)d_in[16];
    const float* wu1_w  = (const float*)d_in[17];
    const float* wu1_b  = (const float*)d_in[18];
    const float* wzu2_w = (const float*)d_in[19];
    const float* wzu2_b = (const float*)d_in[20];
    const float* wz2    = (const float*)d_in[21];
    const float* wyu2_w = (const float*)d_in[22];
    const float* wyu2_b = (const float*)d_in[23];
    const float* wy2    = (const float*)d_in[24];
    // d_in[25]/[26] (wu2_w, wu2_b) shift the value, not the gradient -> unused
    float* out = (float*)d_out;

    picnn_solve<<<dim3(NB), dim3(NTHREADS), 0, stream>>>(
        x, y, wuu0_w, wuu0_b, wyu0_w, wyu0_b, wy0, wu0_w, wu0_b,
        wuu1_w, wuu1_b, wzu1_w, wzu1_b, wz1, wyu1_w, wyu1_b, wy1, wu1_w, wu1_b,
        wzu2_w, wzu2_b, wz2, wyu2_w, wyu2_b, wy2, out);
}

// Round 2
// 156.819 us; speedup vs baseline: 1.0177x; 1.0177x over previous
//
#include <hip/hip_runtime.h>
#include <math.h>

#define NB 256        // batch = grid = 1 block per CU
#define N 128         // DIMX = DIMY = DIMH
#define NTHREADS 512  // 8 waves: thread = (k<<2)|h, k=0..127 row, h=0..3 K-quarter
#define MAX_IT 500
// LDS vectors: 4 slices of 32 floats, each padded to 40-float stride -> slice h
// starts at bank 8h so h-broadcast ds_read_b128s hit disjoint banks.
#define SLICE 40
#define SLOT(k) ((((k) >> 5) * SLICE) + ((k) & 31))
#define LDSVEC (3 * SLICE + 32)

typedef float v2f __attribute__((ext_vector_type(2)));

// packed fp32 FMA: 2 independent fma per inst, per-component order identical
// to the scalar version -> bitwise-identical results.
__device__ __forceinline__ v2f pkfma(v2f a, v2f b, v2f c) {
    asm("v_pk_fma_f32 %0, %1, %2, %0" : "+v"(c) : "v"(a), "v"(b));
    return c;
}

// Cross-lane sums via DPP (no LDS/lgkm wait). 0xB1 = quad_perm(1,0,3,2) ==
// xor1 ; 0x4E = quad_perm(2,3,0,1) == xor2 -> bit-identical to shfl_xor pair.
__device__ __forceinline__ float quad_sum(float p) {
    p += __int_as_float(__builtin_amdgcn_update_dpp(
            0, __float_as_int(p), 0xB1, 0xF, 0xF, true));
    p += __int_as_float(__builtin_amdgcn_update_dpp(
            0, __float_as_int(p), 0x4E, 0xF, 0xF, true));
    return p;
}
// Full 16-lane-row sum: quad_sum then row_ror:4 (0x124) + row_ror:8 (0x128).
__device__ __forceinline__ float row_sum16(float p) {
    p = quad_sum(p);
    p += __int_as_float(__builtin_amdgcn_update_dpp(
            0, __float_as_int(p), 0x124, 0xF, 0xF, true));
    p += __int_as_float(__builtin_amdgcn_update_dpp(
            0, __float_as_int(p), 0x128, 0xF, 0xF, true));
    return p;
}
__device__ __forceinline__ float softplus_f(float s) {
    float e = __expf(-fabsf(s));
    return fmaxf(s, 0.f) + __logf(1.f + e);
}
__device__ __forceinline__ float sigmoid_f(float s) {
    float e = __expf(-fabsf(s));
    float r = 1.f / (1.f + e);
    return s >= 0.f ? r : 1.f - r;
}

// row matvec for precompute: dot of W row k (global) with 128-vector V (LDS,
// slice-padded layout). Each lane sums its 32-slice, quad DPP-combine.
__device__ __forceinline__ float mv_row(const float* __restrict__ W,
                                        const float* __restrict__ V,
                                        int k, int h) {
    const float4* wr = (const float4*)(W + k * N + h * 32);
    const float4* vr = (const float4*)(V + h * SLICE);
    float q0 = 0.f, q1 = 0.f, q2 = 0.f, q3 = 0.f;
#pragma unroll
    for (int i = 0; i < 8; ++i) {
        float4 w = wr[i], v = vr[i];
        q0 = fmaf(w.x, v.x, q0); q1 = fmaf(w.y, v.y, q1);
        q2 = fmaf(w.z, v.z, q2); q3 = fmaf(w.w, v.w, q3);
    }
    return quad_sum((q0 + q1) + (q2 + q3));
}

// launch_bounds(512,1): grid == CU count so only 1 block/CU is resident
// anyway; the (512,2) cap at 128 VGPRs was forcing scratch spills / in-loop
// weight re-loads. At <=256 VGPRs all 6 register-resident weight tiles fit.
__global__ __launch_bounds__(NTHREADS, 1)
void picnn_solve(const float* __restrict__ x, const float* __restrict__ y,
                 const float* __restrict__ wuu0_w, const float* __restrict__ wuu0_b,
                 const float* __restrict__ wyu0_w, const float* __restrict__ wyu0_b,
                 const float* __restrict__ wy0,
                 const float* __restrict__ wu0_w, const float* __restrict__ wu0_b,
                 const float* __restrict__ wuu1_w, const float* __restrict__ wuu1_b,
                 const float* __restrict__ wzu1_w, const float* __restrict__ wzu1_b,
                 const float* __restrict__ wz1,
                 const float* __restrict__ wyu1_w, const float* __restrict__ wyu1_b,
                 const float* __restrict__ wy1,
                 const float* __restrict__ wu1_w, const float* __restrict__ wu1_b,
                 const float* __restrict__ wzu2_w, const float* __restrict__ wzu2_b,
                 const float* __restrict__ wz2,
                 const float* __restrict__ wyu2_w, const float* __restrict__ wyu2_b,
                 const float* __restrict__ wy2,
                 float* __restrict__ out)
{
    const int b = blockIdx.x;
    const int t = threadIdx.x;
    const int k = t >> 2;   // output row 0..127
    const int h = t & 3;    // K-quarter 0..3
    const int lane = t & 63;

    __shared__ __align__(16) float xv[LDSVEC];
    __shared__ __align__(16) float u0v[LDSVEC];
    __shared__ __align__(16) float u1v[LDSVEC];
    __shared__ __align__(16) float a0s[LDSVEC];
    __shared__ __align__(16) float a1s[LDSVEC];
    __shared__ __align__(16) float y1s[LDSVEC];
    __shared__ __align__(16) float t1s[LDSVEC];
    __shared__ __align__(16) float d2s[LDSVEC];
    __shared__ __align__(16) float d1s[LDSVEC];
    __shared__ __align__(16) float rp[32];   // per-16-lane-row residual partials

    if (t < N) xv[SLOT(t)] = x[b * N + t];
    __syncthreads();

    // ---- per-sample iteration-invariant precompute ----
    float u0k = softplus_f(mv_row(wuu0_w, xv, k, h) + wuu0_b[k]);
    float a0k = mv_row(wyu0_w, xv, k, h) + wyu0_b[k];
    float c0  = mv_row(wu0_w,  xv, k, h) + wu0_b[k];
    if (h == 0) { u0v[SLOT(k)] = u0k; a0s[SLOT(k)] = a0k; }
    __syncthreads();

    float u1k = softplus_f(mv_row(wuu1_w, u0v, k, h) + wuu1_b[k]);
    float zu  = softplus_f(mv_row(wzu1_w, u0v, k, h) + wzu1_b[k]);
    float a1k = mv_row(wyu1_w, u0v, k, h) + wyu1_b[k];
    float c1  = mv_row(wu1_w,  u0v, k, h) + wu1_b[k];
    if (h == 0) { u1v[SLOT(k)] = u1k; a1s[SLOT(k)] = a1k; }
    __syncthreads();

    float a2 = mv_row(wyu2_w, u1v, k, h) + wyu2_b[k];
    float e2 = a2 * wy2[k];
    float dp;
    {
        // zu2 = sp(<wzu2_w, u1>): every quad computes the same full dot
        const float4* wr = (const float4*)(wzu2_w + h * 32);
        const float4* vr = (const float4*)(u1v + h * SLICE);
        float q0 = 0.f, q1 = 0.f, q2 = 0.f, q3 = 0.f;
#pragma unroll
        for (int i = 0; i < 8; ++i) {
            float4 w = wr[i], v = vr[i];
            q0 = fmaf(w.x, v.x, q0); q1 = fmaf(w.y, v.y, q1);
            q2 = fmaf(w.z, v.z, q2); q3 = fmaf(w.w, v.w, q3);
        }
        float zu2 = softplus_f(quad_sum((q0 + q1) + (q2 + q3)) + wzu2_b[0]);
        dp = zu2 * fmaxf(wz2[k], 0.f);
    }

    // ---- register-resident weights as v2f pairs ----
    // forward rows (k): wf0 = wy0*diag(a0), wf1 = clip(wz1), wf2 = wy1*diag(a1)
    // backward cols (k): wb0 = wy0, wb1 = clip(wz1), wb2 = wy1
    v2f wf0[16], wf1[16], wf2[16], wb0[16], wb1[16], wb2[16];
    {
        const float4* r0 = (const float4*)(wy0 + k * N + h * 32);
        const float4* r1 = (const float4*)(wz1 + k * N + h * 32);
        const float4* r2 = (const float4*)(wy1 + k * N + h * 32);
#pragma unroll
        for (int i = 0; i < 8; ++i) {
            float4 a = r0[i];
            wf0[2 * i]     = (v2f){a.x, a.y};
            wf0[2 * i + 1] = (v2f){a.z, a.w};
            float4 z = r1[i];
            wf1[2 * i]     = (v2f){fmaxf(z.x, 0.f), fmaxf(z.y, 0.f)};
            wf1[2 * i + 1] = (v2f){fmaxf(z.z, 0.f), fmaxf(z.w, 0.f)};
            float4 c = r2[i];
            wf2[2 * i]     = (v2f){c.x, c.y};
            wf2[2 * i + 1] = (v2f){c.z, c.w};
        }
        // fold iteration-invariant column scalings (done BEFORE wb gathers to
        // keep peak pressure low):
        //   s1  = (wy0 diag(a0)) y1 + c0 ; s2a = (wy1 diag(a1)) y1
        const v2f* a0r = (const v2f*)(a0s + h * SLICE);
        const v2f* a1r = (const v2f*)(a1s + h * SLICE);
#pragma unroll
        for (int i = 0; i < 16; ++i) {
            wf0[i] *= a0r[i];
            wf2[i] *= a1r[i];
        }
#pragma unroll
        for (int i = 0; i < 8; ++i) {
            int r = h * 32 + 4 * i;
            wb0[2 * i]     = (v2f){wy0[(r + 0) * N + k], wy0[(r + 1) * N + k]};
            wb0[2 * i + 1] = (v2f){wy0[(r + 2) * N + k], wy0[(r + 3) * N + k]};
            wb1[2 * i]     = (v2f){fmaxf(wz1[(r + 0) * N + k], 0.f),
                                   fmaxf(wz1[(r + 1) * N + k], 0.f)};
            wb1[2 * i + 1] = (v2f){fmaxf(wz1[(r + 2) * N + k], 0.f),
                                   fmaxf(wz1[(r + 3) * N + k], 0.f)};
            wb2[2 * i]     = (v2f){wy1[(r + 0) * N + k], wy1[(r + 1) * N + k]};
            wb2[2 * i + 1] = (v2f){wy1[(r + 2) * N + k], wy1[(r + 3) * N + k]};
        }
    }

    const float yk = y[b * N + k];
    // Initial guess zeroing the linear part of the residual:
    //   g = 0.5*y1 + e2 + (small NN backprop terms)  ->  y1_0 = 2*(y - e2)
    //   => r_0 = -(NN terms) which is already small.
    float y1v = 2.f * (yk - e2);
    if (h == 0) y1s[SLOT(k)] = y1v;
    __syncthreads();

    // Fixed-step iteration y1 += (y - g(y1)) with alpha = 1.0.
    // alpha=1.25 converged on this data => Hessian eigenvalues mu < 1.6 for
    // all samples => alpha=1.0 has contraction |1-mu| < 0.6 everywhere
    // (vs the observed 0.95 tail under 1.25): strictly safer AND the tail
    // sample converges ~10x faster. tol tightened (||r|| < 5e-4) for margin.
    for (int it = 1; it <= MAX_IT; ++it) {
        // S1: s1 = (wy0 diag(a0)) y1 + c0 ; s2a = (wy1 diag(a1)) y1
        const float4* yr = (const float4*)(y1s + h * SLICE);
        v2f P0 = {0.f, 0.f}, P1 = {0.f, 0.f}, Q0 = {0.f, 0.f}, Q1 = {0.f, 0.f};
#pragma unroll
        for (int i = 0; i < 8; ++i) {
            float4 v = yr[i];
            v2f vl = {v.x, v.y}, vh = {v.z, v.w};
            P0 = pkfma(wf0[2 * i], vl, P0); P1 = pkfma(wf0[2 * i + 1], vh, P1);
            Q0 = pkfma(wf2[2 * i], vl, Q0); Q1 = pkfma(wf2[2 * i + 1], vh, Q1);
        }
        float s1v = quad_sum((P0.x + P0.y) + (P1.x + P1.y)) + c0;
        float s2a = quad_sum((Q0.x + Q0.y) + (Q1.x + Q1.y));
        float e1 = __expf(-fabsf(s1v));
        float z1 = fmaxf(s1v, 0.f) + __logf(1.f + e1);
        float rr1 = 1.f / (1.f + e1);
        float sig1 = (s1v >= 0.f) ? rr1 : 1.f - rr1;
        if (h == 0) t1s[SLOT(k)] = z1 * zu;
        __syncthreads();

        // S2: s2 = t1@wz1c^T + s2a + c1 ; d2 = dp*sigma(s2)
        const float4* t1r = (const float4*)(t1s + h * SLICE);
        P0 = (v2f){0.f, 0.f}; P1 = (v2f){0.f, 0.f};
#pragma unroll
        for (int i = 0; i < 8; ++i) {
            float4 v = t1r[i];
            v2f vl = {v.x, v.y}, vh = {v.z, v.w};
            P0 = pkfma(wf1[2 * i], vl, P0); P1 = pkfma(wf1[2 * i + 1], vh, P1);
        }
        float s2 = quad_sum((P0.x + P0.y) + (P1.x + P1.y)) + s2a + c1;
        float d2 = dp * sigmoid_f(s2);
        if (h == 0) d2s[SLOT(k)] = d2;
        __syncthreads();

        // S3: q = d2@wz1c (cols) ; gc = d2@wy1 (cols) ; d1 = q*zu*sig1
        const float4* d2r = (const float4*)(d2s + h * SLICE);
        P0 = (v2f){0.f, 0.f}; P1 = (v2f){0.f, 0.f};
        Q0 = (v2f){0.f, 0.f}; Q1 = (v2f){0.f, 0.f};
#pragma unroll
        for (int i = 0; i < 8; ++i) {
            float4 d = d2r[i];
            v2f dl = {d.x, d.y}, dh = {d.z, d.w};
            P0 = pkfma(wb1[2 * i], dl, P0); P1 = pkfma(wb1[2 * i + 1], dh, P1);
            Q0 = pkfma(wb2[2 * i], dl, Q0); Q1 = pkfma(wb2[2 * i + 1], dh, Q1);
        }
        float qv = quad_sum((P0.x + P0.y) + (P1.x + P1.y));
        float gc = quad_sum((Q0.x + Q0.y) + (Q1.x + Q1.y));
        float d1 = qv * zu * sig1;
        if (h == 0) d1s[SLOT(k)] = d1;
        __syncthreads();

        // S4: gb = d1@wy0 (cols); g; update; residual row partials; check
        const float4* d1r = (const float4*)(d1s + h * SLICE);
        P0 = (v2f){0.f, 0.f}; P1 = (v2f){0.f, 0.f};
#pragma unroll
        for (int i = 0; i < 8; ++i) {
            float4 d = d1r[i];
            v2f dl = {d.x, d.y}, dh = {d.z, d.w};
            P0 = pkfma(wb0[2 * i], dl, P0); P1 = pkfma(wb0[2 * i + 1], dh, P1);
        }
        float gb = quad_sum((P0.x + P0.y) + (P1.x + P1.y));
        float g = fmaf(0.5f, y1v, e2) + gc * a1k + gb * a0k;
        float rres = yk - g;
        y1v += rres;                        // alpha = 1.0
        if (h == 0) y1s[SLOT(k)] = y1v;
        float rs = row_sum16(rres * rres);  // 4 * sum over this row's 4 k's
        if ((lane & 15) == 0) rp[t >> 4] = rs;
        __syncthreads();
        const float4* rpv = (const float4*)rp;
        float4 ra = (rpv[0] + rpv[1]) + (rpv[2] + rpv[3]);
        float4 rb = (rpv[4] + rpv[5]) + (rpv[6] + rpv[7]);
        float4 u = ra + rb;                 // = 4*||r||^2
        float tot = (u.x + u.y) + (u.z + u.w);
        if (tot < 1e-6f) break;             // per-sample ||r|| < 5e-4
    }

    // out[b] = mean_k(y1 + y)
    __syncthreads();
    float v = row_sum16(y1v + yk);           // 4x duplicated per k
    if ((lane & 15) == 0) rp[t >> 4] = v;
    __syncthreads();
    if (t == 0) {
        const float4* rpv = (const float4*)rp;
        float4 ra = (rpv[0] + rpv[1]) + (rpv[2] + rpv[3]);
        float4 rb = (rpv[4] + rpv[5]) + (rpv[6] + rpv[7]);
        float4 u = ra + rb;
        out[b] = ((u.x + u.y) + (u.z + u.w)) * (1.f / 512.f);
    }
}

extern "C" void kernel_launch(void* const* d_in, const int* in_sizes, int n_in,
                              void* d_out, int out_size, void* d_ws, size_t ws_size,
                              hipStream_t stream) {
    const float* x      = (const float*)d_in[0];
    const float* y      = (const float*)d_in[1];
    const float* wuu0_w = (const float*)d_in[2];
    const float* wuu0_b = (const float*)d_in[3];
    const float* wyu0_w = (const float*)d_in[4];
    const float* wyu0_b = (const float*)d_in[5];
    const float* wy0    = (const float*)d_in[6];
    const float* wu0_w  = (const float*)d_in[7];
    const float* wu0_b  = (const float*)d_in[8];
    const float* wuu1_w = (const float*)d_in[9];
    const float* wuu1_b = (const float*)d_in[10];
    const float* wzu1_w = (const float*)d_in[11];
    const float* wzu1_b = (const float*)d_in[12];
    const float* wz1    = (const float*)d_in[13];
    const float* wyu1_w = (const float*)d_in[14];
    const float* wyu1_b = (const float*)d_in[15];
    const float* wy1    = (const float*)d_in[16];
    const float* wu1_w  = (const float*)d_in[17];
    const float* wu1_b  = (const float*)d_in[18];
    const float* wzu2_w = (const float*)d_in[19];
    const float* wzu2_b = (const float*)d_in[20];
    const float* wz2    = (const float*)d_in[21];
    const float* wyu2_w = (const float*)d_in[22];
    const float* wyu2_b = (const float*)d_in[23];
    const float* wy2    = (const float*)d_in[24];
    // d_in[25]/[26] (wu2_w, wu2_b) shift the value, not the gradient -> unused
    float* out = (float*)d_out;

    picnn_solve<<<dim3(NB), dim3(NTHREADS), 0, stream>>>(
        x, y, wuu0_w, wuu0_b, wyu0_w, wyu0_b, wy0, wu0_w, wu0_b,
        wuu1_w, wuu1_b, wzu1_w, wzu1_b, wz1, wyu1_w, wyu1_b, wy1, wu1_w, wu1_b,
        wzu2_w, wzu2_b, wz2, wyu2_w, wyu2_b, wy2, out);
}